// Round 4
// baseline (324.588 us; speedup 1.0000x reference)
//
#include <hip/hip_runtime.h>
#include <math.h>

// Problem: B=16, T=2048, D=256, gamma=0.9
// out[b,t,d] = S2[t,d] * (x@Wq)[b,t,d]
// S2[t,d] = S[8d + (t>>8)][t&255]   (reshape-scramble)
// S[t>=1] = A[t], S[0] = A[1],  A[t] = gamma*A[t-1] + g[t], A[0]=0 (g[0] := 0)
// g = y @ Wk,  y[t,:] = sum_b w[b,t]*x[b,t,:],  w[b,t] = x[b,t,:] . rowsum(Wv)
//
// R11b: 4-stage fusion from R11, but with a hand-rolled device-scope grid
// barrier (plain launches only -> graph-capture safe; no cooperative API).
// 256 blocks x 256 thr = 1 block/CU (co-resident by construction).
// 2 dispatches: k_init (zero barrier counter) -> k_fused.

#define GAMMA_F 0.9f
#define T_LEN 2048
#define D_DIM 256
#define B_DIM 16

typedef __attribute__((ext_vector_type(8))) short bf16x8;
typedef __attribute__((ext_vector_type(16))) float f32x16;

__device__ inline ushort f2bf(float f) {
    union { float f; unsigned u; } v; v.f = f;
    unsigned r = (v.u + 0x7FFFu + ((v.u >> 16) & 1u)) >> 16;  // RNE
    return (ushort)r;
}

// async global->LDS, 16B per lane; LDS dest = wave-uniform base + lane*16
__device__ __forceinline__ void gload_lds16(const void* g, void* l) {
    __builtin_amdgcn_global_load_lds(
        (const __attribute__((address_space(1))) unsigned int*)g,
        (__attribute__((address_space(3))) unsigned int*)l, 16, 0, 0);
}

// Monotonic grid barrier: release-fence, agent-scope add, spin to target,
// acquire-fence. Requires all blocks resident (256 blocks / 256 CUs).
__device__ __forceinline__ void grid_sync(unsigned* cnt, unsigned target, int tid) {
    __threadfence();              // release: wbl2 — make prior writes visible
    __syncthreads();              // all threads' writes fenced before signal
    if (tid == 0) {
        __hip_atomic_fetch_add(cnt, 1u, __ATOMIC_ACQ_REL, __HIP_MEMORY_SCOPE_AGENT);
        while (__hip_atomic_load(cnt, __ATOMIC_ACQUIRE, __HIP_MEMORY_SCOPE_AGENT) < target)
            __builtin_amdgcn_s_sleep(2);
    }
    __syncthreads();
    __threadfence();              // acquire: inv — no stale L1/L2 lines
}

__global__ void k_init(unsigned* cnt) { *cnt = 0u; }

__global__ __launch_bounds__(256) void k_fused(const float* __restrict__ x,
                                               const float* __restrict__ Wq,
                                               const float* __restrict__ Wk,
                                               const float* __restrict__ Wv,
                                               float* __restrict__ out,
                                               float* __restrict__ ws) {
    // workspace layout
    float* loc    = ws;                        // 524288 f
    float* S2     = loc + 524288;              // 524288 f
    float* carry  = S2 + 524288 + 256;         // 65536 f
    ushort* WqT   = (ushort*)(carry + 65536);  // 65536 us
    ushort* WkT   = WqT + 65536;               // 65536 us
    ushort* ybf   = WkT + 65536;               // 524288 us
    ushort* xbf   = ybf + 524288;              // 8388608 us (16 MB)
    unsigned* cnt = (unsigned*)(ws + 6815744); // 26 MB offset, past all data

    __shared__ char LDSBUF[65536] __attribute__((aligned(128)));

    int bid = blockIdx.x;
    int tid = threadIdx.x;
    int lane = tid & 63, wave = tid >> 6;

    // ================= Stage A: wv_sum + y + xbf (+ W transposes) =============
    {
        float* wv = (float*)LDSBUF;            // 1 KB
        {
            const float4* row4 = (const float4*)(Wv + (size_t)tid * D_DIM);
            float s = 0.f;
#pragma unroll 8
            for (int i = 0; i < 64; ++i) {
                float4 v = row4[i];
                s += v.x + v.y + v.z + v.w;
            }
            wv[tid] = s;
        }
        __syncthreads();
        int d0 = lane * 4;
        float4 wv4 = *(float4*)&wv[d0];

#pragma unroll
        for (int j = 0; j < 2; ++j) {
            int t = bid * 8 + wave * 2 + j;
            float4 xr[B_DIM];
            float w_[B_DIM];
#pragma unroll
            for (int b = 0; b < B_DIM; ++b) {
                xr[b] = *(const float4*)(x + ((size_t)b * T_LEN + t) * D_DIM + d0);
                float p = xr[b].x * wv4.x + xr[b].y * wv4.y +
                          xr[b].z * wv4.z + xr[b].w * wv4.w;
#pragma unroll
                for (int o = 32; o > 0; o >>= 1) p += __shfl_xor(p, o, 64);
                w_[b] = p;
            }
            float4 acc = make_float4(0.f, 0.f, 0.f, 0.f);
#pragma unroll
            for (int b = 0; b < B_DIM; ++b) {
                acc.x += w_[b] * xr[b].x;
                acc.y += w_[b] * xr[b].y;
                acc.z += w_[b] * xr[b].z;
                acc.w += w_[b] * xr[b].w;
                ushort4 sx;
                sx.x = f2bf(xr[b].x); sx.y = f2bf(xr[b].y);
                sx.z = f2bf(xr[b].z); sx.w = f2bf(xr[b].w);
                *(ushort4*)&xbf[((size_t)b * T_LEN + t) * D_DIM + d0] = sx;
            }
            ushort4 ys;
            ys.x = f2bf(acc.x); ys.y = f2bf(acc.y);
            ys.z = f2bf(acc.z); ys.w = f2bf(acc.w);
            *(ushort4*)&ybf[(size_t)t * D_DIM + d0] = ys;
        }

        if (bid < 32) {                        // W transposes (disjoint LDS region)
            float (*tile)[68] = (float(*)[68])(LDSBUF + 2048);
            const float* W = (bid < 16) ? Wq : Wk;
            ushort* WT = (bid < 16) ? WqT : WkT;
            int b = bid & 15;
            int k0 = (b & 3) * 64;
            int n0 = (b >> 2) * 64;
            int r = tid >> 4;
            int c4 = (tid & 15) * 4;
#pragma unroll
            for (int i = 0; i < 4; ++i) {
                float4 v = *(const float4*)(W + (size_t)(k0 + r + 16 * i) * D_DIM + n0 + c4);
                *(float4*)&tile[r + 16 * i][c4] = v;
            }
            __syncthreads();
            int n = tid >> 2;
            int j0 = (tid & 3) * 16;
            ushort tmp[16];
#pragma unroll
            for (int i = 0; i < 16; ++i) tmp[i] = f2bf(tile[j0 + i][n]);
            ushort* dst = WT + (size_t)(n0 + n) * D_DIM + k0 + j0;
#pragma unroll
            for (int i = 0; i < 16; ++i) dst[i] = tmp[i];
        }
    }
    grid_sync(cnt, 256, tid);

    // ================= Stage B: g-GEMM + local scan (blocks 0..127) ===========
    if (bid < 128) {
        ushort* As = (ushort*)LDSBUF;          // 32 KB
        ushort* Bs = (ushort*)(LDSBUF + 32768);
        float* Cs = (float*)LDSBUF;            // alias As
        int mt = bid >> 2;
        int nt = bid & 3;
        int wr = wave >> 1, wc = wave & 1, l31 = lane & 31, lh = lane >> 5;

#pragma unroll
        for (int i = 0; i < 8; ++i) {
            int slot = tid + 256 * i;
            int r = slot >> 5;
            int s2h = slot & 31;
            int rs = r ^ (s2h & 7);
            *(bf16x8*)&As[(s2h * 64 + rs) * 8] =
                *(const bf16x8*)&ybf[(size_t)(mt * 64 + r) * D_DIM + s2h * 8];
            *(bf16x8*)&Bs[(s2h * 64 + rs) * 8] =
                *(const bf16x8*)&WkT[(size_t)(nt * 64 + r) * D_DIM + s2h * 8];
        }
        __syncthreads();

        f32x16 acc;
#pragma unroll
        for (int e = 0; e < 16; ++e) acc[e] = 0.f;
#pragma unroll
        for (int s = 0; s < 16; ++s) {
            int s2h = s * 2 + lh;
            int ra = (wr * 32 + l31) ^ (s2h & 7);
            int rb = (wc * 32 + l31) ^ (s2h & 7);
            bf16x8 a = *(bf16x8*)&As[(s2h * 64 + ra) * 8];
            bf16x8 b = *(bf16x8*)&Bs[(s2h * 64 + rb) * 8];
            acc = __builtin_amdgcn_mfma_f32_32x32x16_bf16(a, b, acc, 0, 0, 0);
        }
        __syncthreads();

#pragma unroll
        for (int reg = 0; reg < 16; ++reg) {
            int rr = (reg & 3) + 8 * (reg >> 2) + 4 * lh;
            Cs[(wr * 32 + rr) * 64 + wc * 32 + l31] = acc[reg];
        }
        __syncthreads();

#pragma unroll
        for (int half = 0; half < 2; ++half) {
            int task = half * 256 + tid;
            int dl = task & 63;
            int cl = task >> 6;
            float a = 0.f;
#pragma unroll
            for (int j = 0; j < 8; ++j) {
                int tl = cl * 8 + j;
                int gt = mt * 64 + tl;
                float v = (gt == 0) ? 0.f : Cs[tl * 64 + dl];
                a = GAMMA_F * a + v;
                loc[(size_t)gt * D_DIM + nt * 64 + dl] = a;
            }
            carry[(size_t)(mt * 8 + cl) * D_DIM + nt * 64 + dl] = a;
        }
    }
    grid_sync(cnt, 512, tid);

    // ================= Stage C: S2 build (blocks 0..63) =======================
    if (bid < 64) {
        float (*Ls)[33] = (float(*)[33])LDSBUF;
        int o = bid >> 3;
        int dseg = bid & 7;
        int r = tid;
        int dstart = dseg * 32;
        const float g8 = 0.43046721f;             // 0.9^8
        const float log2g = -0.15200309344504995f;
        float gp = exp2f((float)(o + 1) * log2g);

        float p = 0.f;
        int j0 = dstart - 32; if (j0 < 0) j0 = 0;
        for (int j = j0; j < dstart; ++j)
            p = p * g8 + carry[(size_t)j * D_DIM + r];

#pragma unroll
        for (int dd = 0; dd < 32; ++dd) {
            int d_ = dstart + dd;
            float Aval = loc[(size_t)(8 * d_ + o) * D_DIM + r] + gp * p;
            if (o == 0 && d_ == 0) Aval = loc[D_DIM + r];   // S[0] = A[1]
            Ls[r][dd] = Aval;
            p = p * g8 + carry[(size_t)d_ * D_DIM + r];
        }
        __syncthreads();

        int rr = tid >> 3;
        int cq = tid & 7;
#pragma unroll
        for (int it = 0; it < 8; ++it) {
            int row = it * 32 + rr;
            float4 v;
            v.x = Ls[row][cq * 4 + 0];
            v.y = Ls[row][cq * 4 + 1];
            v.z = Ls[row][cq * 4 + 2];
            v.w = Ls[row][cq * 4 + 3];
            *(float4*)&S2[(size_t)((o << 8) + row) * D_DIM + dstart + cq * 4] = v;
        }
    }
    grid_sync(cnt, 768, tid);

    // ================= Stage D: qgemm, 2 tiles per block ======================
    {
        ushort (*As)[8 * 128 * 8] = (ushort(*)[8 * 128 * 8])LDSBUF;
        ushort (*Bs)[8 * 128 * 8] = (ushort(*)[8 * 128 * 8])(LDSBUF + 32768);
        int wr = wave >> 1, wc = wave & 1, l31 = lane & 31, lh = lane >> 5;

        for (int rep = 0; rep < 2; ++rep) {
            int v = bid + rep * 256;
            int mb = v >> 1;
            int nb = v & 1;

            f32x16 acc[2][2];
#pragma unroll
            for (int i = 0; i < 2; ++i)
#pragma unroll
                for (int j = 0; j < 2; ++j)
#pragma unroll
                    for (int e = 0; e < 16; ++e) acc[i][j][e] = 0.f;

            const ushort* ab = xbf + (size_t)mb * 128 * D_DIM;
            const ushort* bb = WqT + (size_t)nb * 128 * D_DIM;

#define STAGE(buf, kb)                                                        \
    do {                                                                      \
        _Pragma("unroll")                                                     \
        for (int i = 0; i < 4; ++i) {                                         \
            int slot = i * 256 + tid;            /* 0..1023 = kk*128 + row */ \
            int kk = slot >> 7;                                               \
            int row = slot & 127;                                             \
            int ldsbase = (i * 256 + wave * 64) * 8; /* wave-uniform base */  \
            gload_lds16(ab + (size_t)row * D_DIM + (kb) * 64 + kk * 8,        \
                        &As[buf][ldsbase]);                                   \
            gload_lds16(bb + (size_t)row * D_DIM + (kb) * 64 + kk * 8,        \
                        &Bs[buf][ldsbase]);                                   \
        }                                                                     \
    } while (0)

            __syncthreads();   // Bs region may still be read by prior rep
            STAGE(0, 0);
            __syncthreads();   // buf0 staged (barrier drains vmcnt)

#pragma unroll
            for (int kb = 0; kb < 4; ++kb) {
                int cur = kb & 1;
                if (kb < 3) STAGE(cur ^ 1, kb + 1);
#pragma unroll
                for (int s = 0; s < 4; ++s) {
                    int c0 = (s * 2 + lh) * 128;
                    bf16x8 a0 = *(bf16x8*)&As[cur][(c0 + wr * 64 + l31) * 8];
                    bf16x8 a1 = *(bf16x8*)&As[cur][(c0 + wr * 64 + 32 + l31) * 8];
                    bf16x8 b0 = *(bf16x8*)&Bs[cur][(c0 + wc * 64 + l31) * 8];
                    bf16x8 b1 = *(bf16x8*)&Bs[cur][(c0 + wc * 64 + 32 + l31) * 8];
                    acc[0][0] = __builtin_amdgcn_mfma_f32_32x32x16_bf16(a0, b0, acc[0][0], 0, 0, 0);
                    acc[0][1] = __builtin_amdgcn_mfma_f32_32x32x16_bf16(a0, b1, acc[0][1], 0, 0, 0);
                    acc[1][0] = __builtin_amdgcn_mfma_f32_32x32x16_bf16(a1, b0, acc[1][0], 0, 0, 0);
                    acc[1][1] = __builtin_amdgcn_mfma_f32_32x32x16_bf16(a1, b1, acc[1][1], 0, 0, 0);
                }
                if (kb < 3) __syncthreads();
            }
#undef STAGE

            int t_base = (mb & 15) * 128;
            size_t row_base = (size_t)mb * 128;
#pragma unroll
            for (int mi = 0; mi < 2; ++mi) {
#pragma unroll
                for (int ni = 0; ni < 2; ++ni) {
                    int gn = nb * 128 + wc * 64 + ni * 32 + l31;
#pragma unroll
                    for (int reg = 0; reg < 16; ++reg) {
                        int rr = (reg & 3) + 8 * (reg >> 2) + 4 * lh;
                        int m = wr * 64 + mi * 32 + rr;
                        float s2v = S2[(size_t)(t_base + m) * D_DIM + gn];
                        out[(row_base + m) * D_DIM + gn] = acc[mi][ni][reg] * s2v;
                    }
                }
            }
        }
    }
}

extern "C" void kernel_launch(void* const* d_in, const int* in_sizes, int n_in,
                              void* d_out, int out_size, void* d_ws, size_t ws_size,
                              hipStream_t stream) {
    const float* x  = (const float*)d_in[0];
    const float* Wq = (const float*)d_in[1];
    const float* Wk = (const float*)d_in[2];
    const float* Wv = (const float*)d_in[3];
    float* out = (float*)d_out;
    float* ws = (float*)d_ws;
    unsigned* cnt = (unsigned*)(ws + 6815744);   // must match k_fused

    k_init<<<1, 1, 0, stream>>>(cnt);
    k_fused<<<256, 256, 0, stream>>>(x, Wq, Wk, Wv, out, ws);
}

// Round 5
// 142.741 us; speedup vs baseline: 2.2740x; 2.2740x over previous
//
#include <hip/hip_runtime.h>
#include <math.h>

// Problem: B=16, T=2048, D=256, gamma=0.9
// out[b,t,d] = S2[t,d] * (x@Wq)[b,t,d]
// S2[t,d] = S[8d + (t>>8)][t&255]   (reshape-scramble)
// S[t>=1] = A[t], S[0] = A[1],  A[t] = gamma*A[t-1] + g[t], A[0]=0 (g[0] := 0)
// g = y @ Wk,  y[t,:] = sum_b w[b,t]*x[b,t,:],  w[b,t] = x[b,t,:] . rowsum(Wv)
//
// R12: back to the R10 structure (proven 122.5us; R11b full fusion = 250us,
// latency-crippled at 1 block/CU). Changes vs R10:
//  - gs + S2P merged into ONE kernel (128 blocks) with a hand-rolled
//    128-block barrier (pattern HW-validated in R11b). -1 dispatch.
//  - k_init eliminated: k_prep zeroes the barrier counter. -1 dispatch.
//  - S2P warm-up de-serialized (independent weighted MACs, parallel loads).
// 4 dispatches: prep -> y -> gs_s2p -> qgemm.

#define GAMMA_F 0.9f
#define T_LEN 2048
#define D_DIM 256
#define B_DIM 16

typedef __attribute__((ext_vector_type(8))) short bf16x8;
typedef __attribute__((ext_vector_type(16))) float f32x16;

__device__ inline ushort f2bf(float f) {
    union { float f; unsigned u; } v; v.f = f;
    unsigned r = (v.u + 0x7FFFu + ((v.u >> 16) & 1u)) >> 16;  // RNE
    return (ushort)r;
}

// async global->LDS, 16B per lane; LDS dest = wave-uniform base + lane*16
__device__ __forceinline__ void gload_lds16(const void* g, void* l) {
    __builtin_amdgcn_global_load_lds(
        (const __attribute__((address_space(1))) unsigned int*)g,
        (__attribute__((address_space(3))) unsigned int*)l, 16, 0, 0);
}

// Monotonic grid barrier (all blocks must be resident).
__device__ __forceinline__ void grid_sync(unsigned* cnt, unsigned target, int tid) {
    __threadfence();              // release
    __syncthreads();
    if (tid == 0) {
        __hip_atomic_fetch_add(cnt, 1u, __ATOMIC_ACQ_REL, __HIP_MEMORY_SCOPE_AGENT);
        while (__hip_atomic_load(cnt, __ATOMIC_ACQUIRE, __HIP_MEMORY_SCOPE_AGENT) < target)
            __builtin_amdgcn_s_sleep(2);
    }
    __syncthreads();
    __threadfence();              // acquire
}

// ---------- K1: prep — WqT, WkT (bf16 [n][k]) + wv_sum + cnt=0 ----------
__global__ __launch_bounds__(256) void k_prep(const float* __restrict__ Wq,
                                              const float* __restrict__ Wk,
                                              const float* __restrict__ Wv,
                                              ushort* __restrict__ WqT,
                                              ushort* __restrict__ WkT,
                                              float* __restrict__ wv_sum,
                                              unsigned* __restrict__ cnt) {
    int bid = blockIdx.x;
    int tid = threadIdx.x;
    if (bid == 0 && tid == 0) *cnt = 0u;     // arm barrier for k_gs_s2p
    if (bid < 32) {
        __shared__ float tile[64][68];
        const float* W = (bid < 16) ? Wq : Wk;
        ushort* WT = (bid < 16) ? WqT : WkT;
        int b = bid & 15;
        int k0 = (b & 3) * 64;
        int n0 = (b >> 2) * 64;
        int r = tid >> 4;            // 0..15
        int c4 = (tid & 15) * 4;     // 0..60
#pragma unroll
        for (int i = 0; i < 4; ++i) {
            float4 v = *(const float4*)(W + (size_t)(k0 + r + 16 * i) * D_DIM + n0 + c4);
            *(float4*)&tile[r + 16 * i][c4] = v;
        }
        __syncthreads();
        int n = tid >> 2;            // 0..63
        int j0 = (tid & 3) * 16;     // 0..48
        ushort tmp[16];
#pragma unroll
        for (int i = 0; i < 16; ++i) tmp[i] = f2bf(tile[j0 + i][n]);
        ushort* dst = WT + (size_t)(n0 + n) * D_DIM + k0 + j0;
#pragma unroll
        for (int i = 0; i < 16; ++i) dst[i] = tmp[i];
    } else {
        int j = (bid - 32) * 64 + (tid >> 2);
        int q = tid & 3;
        const float4* row4 = (const float4*)(Wv + (size_t)j * D_DIM + q * 64);
        float s = 0.f;
#pragma unroll
        for (int i = 0; i < 16; ++i) {
            float4 v = row4[i];
            s += v.x + v.y + v.z + v.w;
        }
        s += __shfl_xor(s, 1, 64);
        s += __shfl_xor(s, 2, 64);
        if (q == 0) wv_sum[j] = s;
    }
}

// ---------- K2: y (bf16) + xbf — wave-local, float4, no LDS, no barriers ----------
__global__ __launch_bounds__(256) void k_y(const float* __restrict__ x,
                                           const float* __restrict__ wv_sum,
                                           ushort* __restrict__ ybf,
                                           ushort* __restrict__ xbf) {
    int tid = threadIdx.x;
    int lane = tid & 63;
    int t = blockIdx.x * 4 + (tid >> 6);
    int d0 = lane * 4;
    float4 wv4 = *(const float4*)(wv_sum + d0);

    float4 xr[B_DIM];
    float w[B_DIM];
#pragma unroll
    for (int b = 0; b < B_DIM; ++b) {
        xr[b] = *(const float4*)(x + ((size_t)b * T_LEN + t) * D_DIM + d0);
        float p = xr[b].x * wv4.x + xr[b].y * wv4.y + xr[b].z * wv4.z + xr[b].w * wv4.w;
#pragma unroll
        for (int o = 32; o > 0; o >>= 1) p += __shfl_xor(p, o, 64);
        w[b] = p;   // full-batch dot, broadcast to all lanes
    }

    float4 acc = make_float4(0.f, 0.f, 0.f, 0.f);
#pragma unroll
    for (int b = 0; b < B_DIM; ++b) {
        acc.x += w[b] * xr[b].x;
        acc.y += w[b] * xr[b].y;
        acc.z += w[b] * xr[b].z;
        acc.w += w[b] * xr[b].w;
        ushort4 s;
        s.x = f2bf(xr[b].x); s.y = f2bf(xr[b].y);
        s.z = f2bf(xr[b].z); s.w = f2bf(xr[b].w);
        *(ushort4*)&xbf[((size_t)b * T_LEN + t) * D_DIM + d0] = s;
    }
    ushort4 ys;
    ys.x = f2bf(acc.x); ys.y = f2bf(acc.y);
    ys.z = f2bf(acc.z); ys.w = f2bf(acc.w);
    *(ushort4*)&ybf[(size_t)t * D_DIM + d0] = ys;
}

// ---------- K3: fused g-GEMM + local scan + barrier + S2 build ----------
// Part 1 (128 blocks): C = ybf-tile @ WkT-tile^T, chunk scans -> loc, carry.
// 128-block barrier. Part 2 (blocks 0..63): A = loc + g^(o+1)*prefix -> S2.
__global__ __launch_bounds__(256) void k_gs_s2p(const ushort* __restrict__ ybf,
                                                const ushort* __restrict__ WkT,
                                                float* __restrict__ loc,
                                                float* __restrict__ carry,
                                                float* __restrict__ S2,
                                                unsigned* __restrict__ cnt) {
    __shared__ char LDSBUF[65536] __attribute__((aligned(128)));
    ushort* As = (ushort*)LDSBUF;            // 32 KB  [s2h][row^swz][8]
    ushort* Bs = (ushort*)(LDSBUF + 32768);  // 32 KB
    float* Cs = (float*)LDSBUF;              // 16 KB alias: [tl][dl]
    int bid = blockIdx.x;
    int tid = threadIdx.x, lane = tid & 63, w = tid >> 6;

    // ---- Part 1: gs (all 128 blocks) ----
    {
        int mt = bid >> 2;            // 0..31 (t tile)
        int nt = bid & 3;             // 0..3  (n tile)
        int wr = w >> 1, wc = w & 1, l31 = lane & 31, lh = lane >> 5;

#pragma unroll
        for (int i = 0; i < 8; ++i) {
            int slot = tid + 256 * i;        // 0..2047
            int r = slot >> 5;               // 0..63
            int s2h = slot & 31;             // 0..31
            int rs = r ^ (s2h & 7);          // bank swizzle
            *(bf16x8*)&As[(s2h * 64 + rs) * 8] =
                *(const bf16x8*)&ybf[(size_t)(mt * 64 + r) * D_DIM + s2h * 8];
            *(bf16x8*)&Bs[(s2h * 64 + rs) * 8] =
                *(const bf16x8*)&WkT[(size_t)(nt * 64 + r) * D_DIM + s2h * 8];
        }
        __syncthreads();

        f32x16 acc;
#pragma unroll
        for (int e = 0; e < 16; ++e) acc[e] = 0.f;
#pragma unroll
        for (int s = 0; s < 16; ++s) {
            int s2h = s * 2 + lh;
            int ra = (wr * 32 + l31) ^ (s2h & 7);
            int rb = (wc * 32 + l31) ^ (s2h & 7);
            bf16x8 a = *(bf16x8*)&As[(s2h * 64 + ra) * 8];
            bf16x8 b = *(bf16x8*)&Bs[(s2h * 64 + rb) * 8];
            acc = __builtin_amdgcn_mfma_f32_32x32x16_bf16(a, b, acc, 0, 0, 0);
        }
        __syncthreads();                     // all As/Bs reads done; alias Cs

#pragma unroll
        for (int reg = 0; reg < 16; ++reg) {
            int rr = (reg & 3) + 8 * (reg >> 2) + 4 * lh;
            Cs[(wr * 32 + rr) * 64 + wc * 32 + l31] = acc[reg];
        }
        __syncthreads();

        // scan: 512 (cl, dl) tasks over 256 threads
#pragma unroll
        for (int half = 0; half < 2; ++half) {
            int task = half * 256 + tid;     // 0..511
            int dl = task & 63;              // 0..63
            int cl = task >> 6;              // 0..7
            float a = 0.f;
#pragma unroll
            for (int j = 0; j < 8; ++j) {
                int tl = cl * 8 + j;
                int gt = mt * 64 + tl;
                float v = (gt == 0) ? 0.f : Cs[tl * 64 + dl];
                a = GAMMA_F * a + v;
                loc[(size_t)gt * D_DIM + nt * 64 + dl] = a;
            }
            carry[(size_t)(mt * 8 + cl) * D_DIM + nt * 64 + dl] = a;
        }
    }

    grid_sync(cnt, 128, tid);

    // ---- Part 2: S2 build (blocks 0..63) ----
    if (bid < 64) {
        float (*Ls)[33] = (float(*)[33])LDSBUF;  // 33.8 KB (Cs reads done)
        int o = bid >> 3;                // 0..7
        int dseg = bid & 7;              // 0..7
        int r = tid;                     // 0..255
        int dstart = dseg * 32;
        const float g8 = 0.43046721f;    // 0.9^8
        const float log2g = -0.15200309344504995f;  // log2(0.9)
        float gp = exp2f((float)(o + 1) * log2g);

        // warm-up: 32 chunks before the segment, INDEPENDENT weighted MACs
        // p = sum_{i=1..32} g8^(i-1) * carry[dstart-i][r]  (g8^32 ~ 2e-12)
        float p = 0.f;
        {
            float wgt = 1.f;
#pragma unroll
            for (int i = 1; i <= 32; ++i) {
                if (dstart - i >= 0)
                    p += wgt * carry[(size_t)(dstart - i) * D_DIM + r];
                wgt *= g8;
            }
        }

#pragma unroll
        for (int dd = 0; dd < 32; ++dd) {
            int d_ = dstart + dd;
            float Aval = loc[(size_t)(8 * d_ + o) * D_DIM + r] + gp * p;
            if (o == 0 && d_ == 0) Aval = loc[D_DIM + r];   // S[0] = A[1]
            Ls[r][dd] = Aval;
            p = p * g8 + carry[(size_t)d_ * D_DIM + r];
        }
        __syncthreads();

        // transpose out: thread (rr,cq) writes float4 rows of S2
        int rr = tid >> 3;              // 0..31
        int cq = tid & 7;               // 0..7
#pragma unroll
        for (int it = 0; it < 8; ++it) {
            int row = it * 32 + rr;
            float4 v;
            v.x = Ls[row][cq * 4 + 0];
            v.y = Ls[row][cq * 4 + 1];
            v.z = Ls[row][cq * 4 + 2];
            v.w = Ls[row][cq * 4 + 3];
            *(float4*)&S2[(size_t)((o << 8) + row) * D_DIM + dstart + cq * 4] = v;
        }
    }
}

// ---------- K4: out = (xbf @ WqT^T) * S2 — bf16 GEMM, 2-phase LDS dbuf ----------
__global__ __launch_bounds__(256) void k_qgemm(const ushort* __restrict__ xbf,
                                               const ushort* __restrict__ WqT,
                                               const float* __restrict__ S2,
                                               float* __restrict__ out) {
    __shared__ ushort As[2][8 * 128 * 8];   // 2 x 16 KB  [kk][row][8]
    __shared__ ushort Bs[2][8 * 128 * 8];   // 2 x 16 KB
    int bid = blockIdx.x;
    int mb = bid >> 1;           // 0..255  (M tile)
    int nb = bid & 1;            // 0..1    (N tile)
    int tid = threadIdx.x;
    int lane = tid & 63, w = tid >> 6;
    int wr = w >> 1, wc = w & 1;
    int l31 = lane & 31, lh = lane >> 5;

    f32x16 acc[2][2];
#pragma unroll
    for (int i = 0; i < 2; ++i)
#pragma unroll
        for (int j = 0; j < 2; ++j)
#pragma unroll
            for (int e = 0; e < 16; ++e) acc[i][j][e] = 0.f;

    const ushort* ab = xbf + (size_t)mb * 128 * D_DIM;
    const ushort* bb = WqT + (size_t)nb * 128 * D_DIM;

#define STAGE(buf, kb)                                                        \
    do {                                                                      \
        _Pragma("unroll")                                                     \
        for (int i = 0; i < 4; ++i) {                                         \
            int slot = i * 256 + tid;            /* 0..1023 = kk*128 + row */ \
            int kk = slot >> 7;                                               \
            int row = slot & 127;                                             \
            int ldsbase = (i * 256 + w * 64) * 8; /* wave-uniform base */     \
            gload_lds16(ab + (size_t)row * D_DIM + (kb) * 64 + kk * 8,        \
                        &As[buf][ldsbase]);                                   \
            gload_lds16(bb + (size_t)row * D_DIM + (kb) * 64 + kk * 8,        \
                        &Bs[buf][ldsbase]);                                   \
        }                                                                     \
    } while (0)

    STAGE(0, 0);
    __syncthreads();   // drains vmcnt(0): buf0 staged

#pragma unroll
    for (int kb = 0; kb < 4; ++kb) {
        int cur = kb & 1;
        if (kb < 3) STAGE(cur ^ 1, kb + 1);  // overlap next-tile loads w/ MFMA
#pragma unroll
        for (int s = 0; s < 4; ++s) {
            int c0 = (s * 2 + lh) * 128;
            bf16x8 a0 = *(bf16x8*)&As[cur][(c0 + wr * 64 + l31) * 8];
            bf16x8 a1 = *(bf16x8*)&As[cur][(c0 + wr * 64 + 32 + l31) * 8];
            bf16x8 b0 = *(bf16x8*)&Bs[cur][(c0 + wc * 64 + l31) * 8];
            bf16x8 b1 = *(bf16x8*)&Bs[cur][(c0 + wc * 64 + 32 + l31) * 8];
            acc[0][0] = __builtin_amdgcn_mfma_f32_32x32x16_bf16(a0, b0, acc[0][0], 0, 0, 0);
            acc[0][1] = __builtin_amdgcn_mfma_f32_32x32x16_bf16(a0, b1, acc[0][1], 0, 0, 0);
            acc[1][0] = __builtin_amdgcn_mfma_f32_32x32x16_bf16(a1, b0, acc[1][0], 0, 0, 0);
            acc[1][1] = __builtin_amdgcn_mfma_f32_32x32x16_bf16(a1, b1, acc[1][1], 0, 0, 0);
        }
        if (kb < 3) __syncthreads();  // one barrier/K-step
    }
#undef STAGE

    int t_base = (mb & 15) * 128;
    size_t row_base = (size_t)mb * 128;
#pragma unroll
    for (int mi = 0; mi < 2; ++mi) {
#pragma unroll
        for (int ni = 0; ni < 2; ++ni) {
            int gn = nb * 128 + wc * 64 + ni * 32 + l31;
#pragma unroll
            for (int reg = 0; reg < 16; ++reg) {
                int rr = (reg & 3) + 8 * (reg >> 2) + 4 * lh;
                int m = wr * 64 + mi * 32 + rr;
                float s2v = S2[(size_t)(t_base + m) * D_DIM + gn];
                out[(row_base + m) * D_DIM + gn] = acc[mi][ni][reg] * s2v;
            }
        }
    }
}

extern "C" void kernel_launch(void* const* d_in, const int* in_sizes, int n_in,
                              void* d_out, int out_size, void* d_ws, size_t ws_size,
                              hipStream_t stream) {
    const float* x  = (const float*)d_in[0];
    const float* Wq = (const float*)d_in[1];
    const float* Wk = (const float*)d_in[2];
    const float* Wv = (const float*)d_in[3];
    float* out = (float*)d_out;

    // workspace layout
    float* ws = (float*)d_ws;
    float* loc    = ws;                        // 524288 f
    float* S2     = loc + 524288;              // 524288 f
    float* wv_sum = S2 + 524288;               // 256 f
    float* carry  = wv_sum + 256;              // 65536 f (256 chunks x 256)
    ushort* WqT   = (ushort*)(carry + 65536);  // 65536 us
    ushort* WkT   = WqT + 65536;               // 65536 us
    ushort* ybf   = WkT + 65536;               // 524288 us
    ushort* xbf   = ybf + 524288;              // 8388608 us (16 MB)
    unsigned* cnt = (unsigned*)(ws + 6815744); // past all data

    k_prep<<<36, 256, 0, stream>>>(Wq, Wk, Wv, WqT, WkT, wv_sum, cnt);
    k_y<<<T_LEN / 4, 256, 0, stream>>>(x, wv_sum, ybf, xbf);
    k_gs_s2p<<<128, 256, 0, stream>>>(ybf, WkT, loc, carry, S2, cnt);
    k_qgemm<<<(B_DIM * T_LEN / 128) * 2, 256, 0, stream>>>(xbf, WqT, S2, out);
}

// Round 6
// 116.136 us; speedup vs baseline: 2.7949x; 1.2291x over previous
//
#include <hip/hip_runtime.h>
#include <math.h>

// Problem: B=16, T=2048, D=256, gamma=0.9
// out[b,t,d] = S2[t,d] * (x@Wq)[b,t,d]
// S2[t,d] = S[8d + (t>>8)][t&255]   (reshape-scramble)
// S[t>=1] = A[t], S[0] = A[1],  A[t] = gamma*A[t-1] + g[t], A[0]=0 (g[0] := 0)
// g = y @ Wk,  y[t,:] = sum_b w[b,t]*x[b,t,:],  w[b,t] = x[b,t,:] . rowsum(Wv)
//
// R13: R10 structure (proven 122.5us) minus k_S2P: the A-scan reconstruction
// is folded into the qgemm epilogue. Per qgemm block (mb,nb): o=(mb&15)>>1 is
// constant; chain threads (2 per r) build A[8gn+o][r] = loc + g^(o+1)*P[gn]
// with coalesced loc/carry reads into a swizzled 64KB LDS tile (aliased over
// As/Bs), then the C-write multiplies from LDS. In-kernel grid barrier REMOVED
// (R12 lesson: acquire-fence cold caches cost +20us).
// 4 dispatches: prep -> y -> gs -> qgemm.

#define GAMMA_F 0.9f
#define T_LEN 2048
#define D_DIM 256
#define B_DIM 16

typedef __attribute__((ext_vector_type(8))) short bf16x8;
typedef __attribute__((ext_vector_type(16))) float f32x16;

__device__ inline ushort f2bf(float f) {
    union { float f; unsigned u; } v; v.f = f;
    unsigned r = (v.u + 0x7FFFu + ((v.u >> 16) & 1u)) >> 16;  // RNE
    return (ushort)r;
}

// async global->LDS, 16B per lane; LDS dest = wave-uniform base + lane*16
__device__ __forceinline__ void gload_lds16(const void* g, void* l) {
    __builtin_amdgcn_global_load_lds(
        (const __attribute__((address_space(1))) unsigned int*)g,
        (__attribute__((address_space(3))) unsigned int*)l, 16, 0, 0);
}

// ---------- K1: prep — WqT, WkT (bf16 [n][k]) + wv_sum ----------
__global__ __launch_bounds__(256) void k_prep(const float* __restrict__ Wq,
                                              const float* __restrict__ Wk,
                                              const float* __restrict__ Wv,
                                              ushort* __restrict__ WqT,
                                              ushort* __restrict__ WkT,
                                              float* __restrict__ wv_sum) {
    int bid = blockIdx.x;
    int tid = threadIdx.x;
    if (bid < 32) {
        __shared__ float tile[64][68];
        const float* W = (bid < 16) ? Wq : Wk;
        ushort* WT = (bid < 16) ? WqT : WkT;
        int b = bid & 15;
        int k0 = (b & 3) * 64;
        int n0 = (b >> 2) * 64;
        int r = tid >> 4;            // 0..15
        int c4 = (tid & 15) * 4;     // 0..60
#pragma unroll
        for (int i = 0; i < 4; ++i) {
            float4 v = *(const float4*)(W + (size_t)(k0 + r + 16 * i) * D_DIM + n0 + c4);
            *(float4*)&tile[r + 16 * i][c4] = v;
        }
        __syncthreads();
        int n = tid >> 2;            // 0..63
        int j0 = (tid & 3) * 16;     // 0..48
        ushort tmp[16];
#pragma unroll
        for (int i = 0; i < 16; ++i) tmp[i] = f2bf(tile[j0 + i][n]);
        ushort* dst = WT + (size_t)(n0 + n) * D_DIM + k0 + j0;
#pragma unroll
        for (int i = 0; i < 16; ++i) dst[i] = tmp[i];
    } else {
        int j = (bid - 32) * 64 + (tid >> 2);
        int q = tid & 3;
        const float4* row4 = (const float4*)(Wv + (size_t)j * D_DIM + q * 64);
        float s = 0.f;
#pragma unroll
        for (int i = 0; i < 16; ++i) {
            float4 v = row4[i];
            s += v.x + v.y + v.z + v.w;
        }
        s += __shfl_xor(s, 1, 64);
        s += __shfl_xor(s, 2, 64);
        if (q == 0) wv_sum[j] = s;
    }
}

// ---------- K2: y (bf16) + xbf — wave-local, float4, no LDS, no barriers ----------
__global__ __launch_bounds__(256) void k_y(const float* __restrict__ x,
                                           const float* __restrict__ wv_sum,
                                           ushort* __restrict__ ybf,
                                           ushort* __restrict__ xbf) {
    int tid = threadIdx.x;
    int lane = tid & 63;
    int t = blockIdx.x * 4 + (tid >> 6);
    int d0 = lane * 4;
    float4 wv4 = *(const float4*)(wv_sum + d0);

    float4 xr[B_DIM];
    float w[B_DIM];
#pragma unroll
    for (int b = 0; b < B_DIM; ++b) {
        xr[b] = *(const float4*)(x + ((size_t)b * T_LEN + t) * D_DIM + d0);
        float p = xr[b].x * wv4.x + xr[b].y * wv4.y + xr[b].z * wv4.z + xr[b].w * wv4.w;
#pragma unroll
        for (int o = 32; o > 0; o >>= 1) p += __shfl_xor(p, o, 64);
        w[b] = p;   // full-batch dot, broadcast to all lanes
    }

    float4 acc = make_float4(0.f, 0.f, 0.f, 0.f);
#pragma unroll
    for (int b = 0; b < B_DIM; ++b) {
        acc.x += w[b] * xr[b].x;
        acc.y += w[b] * xr[b].y;
        acc.z += w[b] * xr[b].z;
        acc.w += w[b] * xr[b].w;
        ushort4 s;
        s.x = f2bf(xr[b].x); s.y = f2bf(xr[b].y);
        s.z = f2bf(xr[b].z); s.w = f2bf(xr[b].w);
        *(ushort4*)&xbf[((size_t)b * T_LEN + t) * D_DIM + d0] = s;
    }
    ushort4 ys;
    ys.x = f2bf(acc.x); ys.y = f2bf(acc.y);
    ys.z = f2bf(acc.z); ys.w = f2bf(acc.w);
    *(ushort4*)&ybf[(size_t)t * D_DIM + d0] = ys;
}

// ---------- K3: fused g-GEMM + local scan (128 blocks) ----------
__global__ __launch_bounds__(256) void k_gs(const ushort* __restrict__ ybf,
                                            const ushort* __restrict__ WkT,
                                            float* __restrict__ loc,
                                            float* __restrict__ carry) {
    __shared__ ushort As[32 * 64 * 8];   // 32 KB  [s2h][row^swz][8]
    __shared__ ushort Bs[32 * 64 * 8];   // 32 KB
    float* Cs = (float*)As;              // 16 KB alias: [tl=0..63][dl=0..63]
    int mt = blockIdx.x >> 2;            // 0..31 (t tile)
    int nt = blockIdx.x & 3;             // 0..3  (n tile)
    int tid = threadIdx.x, lane = tid & 63, w = tid >> 6;
    int wr = w >> 1, wc = w & 1, l31 = lane & 31, lh = lane >> 5;

#pragma unroll
    for (int i = 0; i < 8; ++i) {
        int slot = tid + 256 * i;        // 0..2047
        int r = slot >> 5;               // 0..63
        int s2h = slot & 31;             // 0..31
        int rs = r ^ (s2h & 7);          // bank swizzle
        *(bf16x8*)&As[(s2h * 64 + rs) * 8] =
            *(const bf16x8*)&ybf[(size_t)(mt * 64 + r) * D_DIM + s2h * 8];
        *(bf16x8*)&Bs[(s2h * 64 + rs) * 8] =
            *(const bf16x8*)&WkT[(size_t)(nt * 64 + r) * D_DIM + s2h * 8];
    }
    __syncthreads();

    f32x16 acc;
#pragma unroll
    for (int e = 0; e < 16; ++e) acc[e] = 0.f;
#pragma unroll
    for (int s = 0; s < 16; ++s) {
        int s2h = s * 2 + lh;
        int ra = (wr * 32 + l31) ^ (s2h & 7);
        int rb = (wc * 32 + l31) ^ (s2h & 7);
        bf16x8 a = *(bf16x8*)&As[(s2h * 64 + ra) * 8];
        bf16x8 b = *(bf16x8*)&Bs[(s2h * 64 + rb) * 8];
        acc = __builtin_amdgcn_mfma_f32_32x32x16_bf16(a, b, acc, 0, 0, 0);
    }
    __syncthreads();                     // all As/Bs reads done; alias Cs

#pragma unroll
    for (int reg = 0; reg < 16; ++reg) {
        int rr = (reg & 3) + 8 * (reg >> 2) + 4 * lh;
        Cs[(wr * 32 + rr) * 64 + wc * 32 + l31] = acc[reg];
    }
    __syncthreads();

    // scan: 512 (cl, dl) tasks over 256 threads
#pragma unroll
    for (int half = 0; half < 2; ++half) {
        int task = half * 256 + tid;     // 0..511
        int dl = task & 63;              // 0..63
        int cl = task >> 6;              // 0..7
        float a = 0.f;
#pragma unroll
        for (int j = 0; j < 8; ++j) {
            int tl = cl * 8 + j;
            int gt = mt * 64 + tl;
            float v = (gt == 0) ? 0.f : Cs[tl * 64 + dl];
            a = GAMMA_F * a + v;
            loc[(size_t)gt * D_DIM + nt * 64 + dl] = a;
        }
        carry[(size_t)(mt * 8 + cl) * D_DIM + nt * 64 + dl] = a;
    }
}

// ---------- K4: out = (xbf @ WqT^T) * A-scan — GEMM + fused S2 epilogue ----------
// Block (mb, nb): o = (mb&15)>>1 constant; rows r = (mb&1)*128 + m.
// Epilogue chain (256 thr, 2 per r) builds Av[gn][r] = loc[8gn+o][r] +
// g^(o+1)*P[gn][r] into swizzled LDS (P = 32-term-truncated chunk prefix),
// then C-write multiplies acc by Av from LDS.
__global__ __launch_bounds__(256) void k_qgemm(const ushort* __restrict__ xbf,
                                               const ushort* __restrict__ WqT,
                                               const float* __restrict__ loc,
                                               const float* __restrict__ carry,
                                               float* __restrict__ out) {
    __shared__ char QL[65536] __attribute__((aligned(128)));
    int bid = blockIdx.x;
    int mb = bid >> 1;           // 0..255  (M tile)
    int nb = bid & 1;            // 0..1    (N tile)
    int tid = threadIdx.x;
    int lane = tid & 63, w = tid >> 6;
    int wr = w >> 1, wc = w & 1;
    int l31 = lane & 31, lh = lane >> 5;

    f32x16 acc[2][2];
#pragma unroll
    for (int i = 0; i < 2; ++i)
#pragma unroll
        for (int j = 0; j < 2; ++j)
#pragma unroll
            for (int e = 0; e < 16; ++e) acc[i][j][e] = 0.f;

    const ushort* ab = xbf + (size_t)mb * 128 * D_DIM;
    const ushort* bb = WqT + (size_t)nb * 128 * D_DIM;

    // LDS carve: As[buf] @ buf*16KB, Bs[buf] @ 32KB + buf*16KB  ([kk][row][8])
#define ASP(buf) ((ushort*)(QL + (buf) * 16384))
#define BSP(buf) ((ushort*)(QL + 32768 + (buf) * 16384))
#define STAGE(buf, kb)                                                        \
    do {                                                                      \
        _Pragma("unroll")                                                     \
        for (int i = 0; i < 4; ++i) {                                         \
            int slot = i * 256 + tid;            /* 0..1023 = kk*128 + row */ \
            int kk = slot >> 7;                                               \
            int row = slot & 127;                                             \
            int ldsbase = (i * 256 + w * 64) * 8; /* wave-uniform base */     \
            gload_lds16(ab + (size_t)row * D_DIM + (kb) * 64 + kk * 8,        \
                        ASP(buf) + ldsbase);                                  \
            gload_lds16(bb + (size_t)row * D_DIM + (kb) * 64 + kk * 8,        \
                        BSP(buf) + ldsbase);                                  \
        }                                                                     \
    } while (0)

    STAGE(0, 0);
    __syncthreads();   // drains vmcnt(0): buf0 staged

#pragma unroll
    for (int kb = 0; kb < 4; ++kb) {
        int cur = kb & 1;
        if (kb < 3) STAGE(cur ^ 1, kb + 1);  // overlap next-tile loads w/ MFMA
#pragma unroll
        for (int s = 0; s < 4; ++s) {
            int c0 = (s * 2 + lh) * 128;
            bf16x8 a0 = *(bf16x8*)&ASP(cur)[(c0 + wr * 64 + l31) * 8];
            bf16x8 a1 = *(bf16x8*)&ASP(cur)[(c0 + wr * 64 + 32 + l31) * 8];
            bf16x8 b0 = *(bf16x8*)&BSP(cur)[(c0 + wc * 64 + l31) * 8];
            bf16x8 b1 = *(bf16x8*)&BSP(cur)[(c0 + wc * 64 + 32 + l31) * 8];
            acc[0][0] = __builtin_amdgcn_mfma_f32_32x32x16_bf16(a0, b0, acc[0][0], 0, 0, 0);
            acc[0][1] = __builtin_amdgcn_mfma_f32_32x32x16_bf16(a0, b1, acc[0][1], 0, 0, 0);
            acc[1][0] = __builtin_amdgcn_mfma_f32_32x32x16_bf16(a1, b0, acc[1][0], 0, 0, 0);
            acc[1][1] = __builtin_amdgcn_mfma_f32_32x32x16_bf16(a1, b1, acc[1][1], 0, 0, 0);
        }
        if (kb < 3) __syncthreads();  // one barrier/K-step
    }
#undef STAGE
#undef ASP
#undef BSP

    __syncthreads();                 // all MFMA LDS reads done; alias Av tile

    // ---- fused S2P: build Av[gn_local][r_local] in LDS (64 KB, swizzled) ----
    float* Ls = (float*)QL;          // word index: rloc*128 + (gnl ^ (rloc&31))
    {
        int rloc = tid & 127;            // r_local 0..127
        int h = tid >> 7;                // wave-uniform gn-half
        int rglob = (mb & 1) * 128 + rloc;
        int o = (mb & 15) >> 1;
        int gn0 = nb * 128;
        int gstart = gn0 + h * 64;       // 0,64,128,192
        const float g8 = 0.43046721f;    // 0.9^8
        const float log2g = -0.15200309344504995f;  // log2(0.9)
        float gpo = exp2f((float)(o + 1) * log2g);  // gamma^(o+1)

        // warm-up: P[gstart] = sum_{i=1..32} g8^(i-1) carry[gstart-i][rglob]
        // (g8^32 ~ 2e-12: exact to f32; gstart==0 -> P=0)
        float p = 0.f;
        if (gstart > 0) {
            float wgt = 1.f;
#pragma unroll
            for (int i = 1; i <= 32; ++i) {
                p += wgt * carry[(size_t)(gstart - i) * D_DIM + rglob];
                wgt *= g8;
            }
        }
#pragma unroll 8
        for (int gl = 0; gl < 64; ++gl) {
            int gn = gstart + gl;
            float locv = loc[(size_t)(8 * gn + o) * D_DIM + rglob];  // coalesced over rloc
            float Av = fmaf(gpo, p, locv);
            if (o == 0 && gn == 0) Av = loc[D_DIM + rglob];          // S[0] = A[1]
            int gnl = gn - gn0;
            Ls[rloc * 128 + (gnl ^ (rloc & 31))] = Av;
            p = p * g8 + carry[(size_t)gn * D_DIM + rglob];          // P[gn+1]
        }
    }
    __syncthreads();

    // ---- C-write: out = acc * Av ----
    size_t row_base = (size_t)mb * 128;
#pragma unroll
    for (int mi = 0; mi < 2; ++mi) {
#pragma unroll
        for (int ni = 0; ni < 2; ++ni) {
            int gnl = wc * 64 + ni * 32 + l31;        // col within tile
            int gn_out = nb * 128 + gnl;
#pragma unroll
            for (int reg = 0; reg < 16; ++reg) {
                int rr = (reg & 3) + 8 * (reg >> 2) + 4 * lh;
                int m = wr * 64 + mi * 32 + rr;       // row within tile = r_local
                float av = Ls[m * 128 + (gnl ^ (m & 31))];
                out[(row_base + m) * D_DIM + gn_out] = acc[mi][ni][reg] * av;
            }
        }
    }
}

extern "C" void kernel_launch(void* const* d_in, const int* in_sizes, int n_in,
                              void* d_out, int out_size, void* d_ws, size_t ws_size,
                              hipStream_t stream) {
    const float* x  = (const float*)d_in[0];
    const float* Wq = (const float*)d_in[1];
    const float* Wk = (const float*)d_in[2];
    const float* Wv = (const float*)d_in[3];
    float* out = (float*)d_out;

    // workspace layout (S2 slot retained but unused; offsets unchanged)
    float* ws = (float*)d_ws;
    float* loc    = ws;                        // 524288 f
    float* wv_sum = ws + 1048576 + 256 - 256;  // = old S2+524288 slot start
    wv_sum = ws + 1048576;                     // 256 f (old wv_sum position)
    float* carry  = wv_sum + 256;              // 65536 f (256 chunks x 256)
    ushort* WqT   = (ushort*)(carry + 65536);  // 65536 us
    ushort* WkT   = WqT + 65536;               // 65536 us
    ushort* ybf   = WkT + 65536;               // 524288 us
    ushort* xbf   = ybf + 524288;              // 8388608 us (16 MB)

    k_prep<<<36, 256, 0, stream>>>(Wq, Wk, Wv, WqT, WkT, wv_sum);
    k_y<<<T_LEN / 4, 256, 0, stream>>>(x, wv_sum, ybf, xbf);
    k_gs<<<128, 256, 0, stream>>>(ybf, WkT, loc, carry);
    k_qgemm<<<(B_DIM * T_LEN / 128) * 2, 256, 0, stream>>>(xbf, WqT, loc, carry, out);
}